// Round 2
// baseline (453.612 us; speedup 1.0000x reference)
//
#include <hip/hip_runtime.h>
#include <hip/hip_bf16.h>

#define NN 100000
#define EE 1600000

constexpr int SCAN_BLK = 1024;                       // elements per scan block (256 thr * 4)
constexpr int NB_SCAN  = (NN + SCAN_BLK - 1) / SCAN_BLK;  // 98

// LDS counting-sort CSR build: 8 dst-ranges x 32 edge-chunks
constexpr int NR2 = 8;              // dst ranges (12500 nodes -> 50 KB LDS histogram)
constexpr int RSZ = NN / NR2;       // 12500
constexpr int CH  = 32;             // edge chunks
constexpr int CSZ = EE / CH;        // 50000 edges per chunk

// ---------------- CSR build (no global atomics) ----------------

__global__ __launch_bounds__(256) void histL_k(const int* __restrict__ ei,
                                               int* __restrict__ CntG) {
    __shared__ int cnt[RSZ];
    int r = blockIdx.x % NR2, c = blockIdx.x / NR2;
    int lo = r * RSZ;
    for (int t = threadIdx.x; t < RSZ; t += 256) cnt[t] = 0;
    __syncthreads();
    const int* __restrict__ dstp = ei + EE;
    int base = c * CSZ;
    int tid = threadIdx.x;
    for (int ii = 0; ii < CSZ; ii += 1024) {
        int d[4], s[4];
        #pragma unroll
        for (int k = 0; k < 4; ++k) {
            int off = ii + tid + k * 256;
            bool v = off < CSZ;
            d[k] = v ? dstp[base + off] : -1;
            s[k] = v ? ei[base + off]   : -1;
        }
        #pragma unroll
        for (int k = 0; k < 4; ++k) {
            int dl = d[k] - lo;
            if (dl >= 0 && dl < RSZ && s[k] != d[k]) atomicAdd(&cnt[dl], 1);
        }
    }
    __syncthreads();
    for (int t = threadIdx.x; t < RSZ; t += 256)
        CntG[(size_t)c * NN + lo + t] = cnt[t];
}

__global__ void combineL_k(int* __restrict__ CntG, int* __restrict__ deg) {
    int d = blockIdx.x * 256 + threadIdx.x;
    if (d < NN) {
        int run = 0;
        #pragma unroll 8
        for (int c = 0; c < CH; ++c) {
            int v = CntG[(size_t)c * NN + d];
            CntG[(size_t)c * NN + d] = run;
            run += v;
        }
        deg[d] = run;
    }
}

__global__ void sum_blocks(const int* __restrict__ deg, int* __restrict__ partials) {
    __shared__ int sh[256];
    int t = threadIdx.x;
    int base = blockIdx.x * SCAN_BLK + t * 4;
    int s = 0;
    #pragma unroll
    for (int k = 0; k < 4; ++k) { int i = base + k; if (i < NN) s += deg[i]; }
    sh[t] = s; __syncthreads();
    for (int off = 128; off > 0; off >>= 1) {
        if (t < off) sh[t] += sh[t + off];
        __syncthreads();
    }
    if (t == 0) partials[blockIdx.x] = sh[0];
}

__global__ void scan_partials(int* __restrict__ partials) {
    __shared__ int sh[128];
    int t = threadIdx.x;
    int v = (t < NB_SCAN) ? partials[t] : 0;
    sh[t] = v;
    __syncthreads();
    for (int off = 1; off < 128; off <<= 1) {
        int tmp = (t >= off) ? sh[t - off] : 0;
        __syncthreads();
        sh[t] += tmp;
        __syncthreads();
    }
    if (t < NB_SCAN) partials[t] = sh[t] - v;   // exclusive prefix
}

__global__ void scan_final(const int* __restrict__ deg, const int* __restrict__ partials,
                           int* __restrict__ rowptr) {
    __shared__ int sh[256];
    int t = threadIdx.x;
    int base = blockIdx.x * SCAN_BLK + t * 4;
    int v[4]; int s = 0;
    #pragma unroll
    for (int k = 0; k < 4; ++k) { int i = base + k; v[k] = (i < NN) ? deg[i] : 0; s += v[k]; }
    sh[t] = s; __syncthreads();
    for (int off = 1; off < 256; off <<= 1) {
        int tmp = (t >= off) ? sh[t - off] : 0;
        __syncthreads();
        sh[t] += tmp;
        __syncthreads();
    }
    int pref = partials[blockIdx.x] + sh[t] - s;
    #pragma unroll
    for (int k = 0; k < 4; ++k) {
        int i = base + k;
        if (i < NN) {
            rowptr[i] = pref; pref += v[k];
            if (i == NN - 1) rowptr[NN] = pref;
        }
    }
}

__global__ __launch_bounds__(256) void scatterL_k(const int* __restrict__ ei,
                                                  const int* __restrict__ CntG,
                                                  const int* __restrict__ rowptr,
                                                  int* __restrict__ col) {
    __shared__ int cur[RSZ];
    int r = blockIdx.x % NR2, c = blockIdx.x / NR2;
    int lo = r * RSZ;
    for (int t = threadIdx.x; t < RSZ; t += 256)
        cur[t] = rowptr[lo + t] + CntG[(size_t)c * NN + lo + t];
    __syncthreads();
    const int* __restrict__ dstp = ei + EE;
    int base = c * CSZ;
    int tid = threadIdx.x;
    for (int ii = 0; ii < CSZ; ii += 1024) {
        int d[4], s[4];
        #pragma unroll
        for (int k = 0; k < 4; ++k) {
            int off = ii + tid + k * 256;
            bool v = off < CSZ;
            d[k] = v ? dstp[base + off] : -1;
            s[k] = v ? ei[base + off]   : -1;
        }
        #pragma unroll
        for (int k = 0; k < 4; ++k) {
            int dl = d[k] - lo;
            if (dl >= 0 && dl < RSZ && s[k] != d[k]) {
                int p = atomicAdd(&cur[dl], 1);
                col[p] = s[k];
            }
        }
    }
}

// ---------------- GEMM (h = x @ W) + per-node attention arrays ----------------

template<int K, int M, int H, int NPB>
__global__ __launch_bounds__(256) void gemm_tile(const float* __restrict__ xin,
                          const float* __restrict__ W,
                          const float* __restrict__ att,
                          uint2* __restrict__ Hbf,
                          float* __restrict__ ssrcA,
                          float* __restrict__ sdst) {
    constexpr int C   = M / H;
    constexpr int MG  = M / 4;               // col-groups (4 cols per thread)
    constexpr int NG  = NPB / 4;
    static_assert(MG * NG == 256, "tile mismatch");
    constexpr int K4  = K / 4;
    constexpr int KC4 = (K4 > 16) ? 16 : K4;
    constexpr int NCH = K4 / KC4;

    __shared__ float4 Wq[K * MG];
    __shared__ float4 Xq[NPB * KC4];

    int tid = threadIdx.x;
    const float4* W4 = (const float4*)W;
    for (int i = tid; i < K * MG; i += 256) Wq[i] = W4[i];

    int node0 = blockIdx.x * NPB;
    const float4* x4 = (const float4*)xin;

    int mg = tid % MG, ng = tid / MG;
    int nb = ng * 4;
    float acc[4][4];
    #pragma unroll
    for (int i = 0; i < 4; ++i)
        #pragma unroll
        for (int j = 0; j < 4; ++j) acc[i][j] = 0.f;

    for (int ch = 0; ch < NCH; ++ch) {
        __syncthreads();
        for (int i = tid; i < NPB * KC4; i += 256) {
            int n = i / KC4, k4l = i % KC4;
            int node = node0 + n;
            float4 v = make_float4(0.f, 0.f, 0.f, 0.f);
            if (node < NN) v = x4[(size_t)node * K4 + ch * KC4 + k4l];
            Xq[i] = v;
        }
        __syncthreads();
        #pragma unroll 4
        for (int k4 = 0; k4 < KC4; ++k4) {
            float4 xv[4], wv[4];
            #pragma unroll
            for (int i = 0; i < 4; ++i) xv[i] = Xq[(nb + i) * KC4 + k4];
            int kbase = (ch * KC4 + k4) * 4;
            #pragma unroll
            for (int kk = 0; kk < 4; ++kk) wv[kk] = Wq[(kbase + kk) * MG + mg];
            #pragma unroll
            for (int i = 0; i < 4; ++i) {
                const float* xf = (const float*)&xv[i];
                #pragma unroll
                for (int kk = 0; kk < 4; ++kk) {
                    const float* wf = (const float*)&wv[kk];
                    float xs = xf[kk];
                    acc[i][0] = fmaf(xs, wf[0], acc[i][0]);
                    acc[i][1] = fmaf(xs, wf[1], acc[i][1]);
                    acc[i][2] = fmaf(xs, wf[2], acc[i][2]);
                    acc[i][3] = fmaf(xs, wf[3], acc[i][3]);
                }
            }
        }
    }

    constexpr int TPH = C / 4;               // threads covering one head's cols
    int head = mg / TPH;
    int c0   = (mg % TPH) * 4;
    float ad[4], as_[4];
    #pragma unroll
    for (int j = 0; j < 4; ++j) {
        ad[j]  = att[head * 2 * C + c0 + j];
        as_[j] = att[head * 2 * C + C + c0 + j];
    }
    #pragma unroll
    for (int i = 0; i < 4; ++i) {
        int node = node0 + nb + i;
        if (node < NN) {
            unsigned short us[4];
            #pragma unroll
            for (int j = 0; j < 4; ++j) {
                __hip_bfloat16 b = __float2bfloat16(acc[i][j]);
                us[j] = *(unsigned short*)&b;
            }
            uint2 pk;
            pk.x = (unsigned)us[0] | ((unsigned)us[1] << 16);
            pk.y = (unsigned)us[2] | ((unsigned)us[3] << 16);
            Hbf[(size_t)node * MG + mg] = pk;
        }
        float pd = acc[i][0]*ad[0]  + acc[i][1]*ad[1]  + acc[i][2]*ad[2]  + acc[i][3]*ad[3];
        float ps = acc[i][0]*as_[0] + acc[i][1]*as_[1] + acc[i][2]*as_[2] + acc[i][3]*as_[3];
        #pragma unroll
        for (int off = 1; off < TPH; off <<= 1) {
            pd += __shfl_xor(pd, off, 64);
            ps += __shfl_xor(ps, off, 64);
        }
        if ((mg % TPH) == 0 && node < NN) {
            sdst[node * H + head]  = pd;
            ssrcA[node * H + head] = ps;
        }
    }
}

// ---------------- Aggregation: one wave per TWO nodes, interleaved ------------
// Dual-node ILP: both nodes' col loads issued together, then both nodes' ssrcA
// loads + all Hbf gathers in flight before any exp/FMA consumes them. Gathers
// are UNCONDITIONAL within a wave-uniform per-node guard (dead edge slots are
// clamped to the node's own row and zero-weighted) — this preserves the
// back-to-back load issue pattern that round-0's per-group guards destroyed.
// Virtual self-loop handled in the prologue (own row read is coalesced).

template<int CT, int H, int U, bool ELU_OUT>
__global__ __launch_bounds__(256) void agg_k(const int* __restrict__ rowptr, const int* __restrict__ col,
                      const float* __restrict__ sdst, const float* __restrict__ ssrcA,
                      const uint2* __restrict__ Hbf,
                      const float* __restrict__ bias, float* __restrict__ output) {
    constexpr int C    = CT / H;         // channels per head
    constexpr int CP   = CT / 4;         // lanes covering one row (uint2 = 4 ch)
    constexpr int G    = 64 / CP;        // edge slots per gather instruction
    constexpr int NL   = U / G;          // row gathers in flight per lane (per node)
    constexpr int EPEL = (U * H >= 64) ? (U * H) / 64 : 1;   // edges per exp lane
    static_assert(EPEL == 1 || EPEL == 2, "mapping");

    int lane = threadIdx.x & 63;
    int wid  = threadIdx.x >> 6;
    int nA = blockIdx.x * ((blockDim.x >> 6) * 2) + wid * 2;
    if (nA >= NN) return;
    int nB = nA + 1;
    bool hasB = (nB < NN);

    int cp = lane % CP;                  // channel quad {4cp..4cp+3}
    int pp = lane / CP;                  // gather slot parity (0..G-1)
    int hh = (4 * cp) / C;               // head of these channels (uniform in quad)
    int eh = lane % H;                   // exp-lane head
    int gb = lane / H;                   // exp-lane base edge slot
    bool elane = (lane < U * H);         // exp-lane mask (EPEL==1 case)

    float sdA = elane ? sdst[nA * H + eh] : 0.f;
    float sdB = (hasB && elane) ? sdst[nB * H + eh] : 0.f;

    int startA = rowptr[nA], endA = rowptr[nA + 1];
    int startB = 0, endB = 0;
    if (hasB) { startB = endA; endB = rowptr[nB + 1]; }

    // ---- virtual self-loops: score + own-row contribution ----
    float dsumA = 0.f, dsumB = 0.f;
    float esA = 0.f, esB = 0.f;
    if (lane < H) {                      // lane == eh here
        float ss = ssrcA[nA * H + lane];
        float a = sdA + ss; a = (a >= 0.f) ? a : 0.2f * a;
        esA = __expf(a);
        dsumA = esA;
    }
    if (hasB && lane < H) {
        float ss = ssrcA[nB * H + lane];
        float a = sdB + ss; a = (a >= 0.f) ? a : 0.2f * a;
        esB = __expf(a);
        dsumB = esB;
    }
    uint2 hsA = Hbf[(size_t)nA * CP + cp];
    uint2 hsB = make_uint2(0u, 0u);
    if (hasB) hsB = Hbf[(size_t)nB * CP + cp];
    float exsA = __shfl(esA, hh, 64);
    float exsB = __shfl(esB, hh, 64);
    float4 accA = make_float4(0.f, 0.f, 0.f, 0.f);
    float4 accB = make_float4(0.f, 0.f, 0.f, 0.f);
    if (pp == 0) {                       // count self row exactly once
        accA.x = exsA * __uint_as_float(hsA.x << 16);
        accA.y = exsA * __uint_as_float(hsA.x & 0xffff0000u);
        accA.z = exsA * __uint_as_float(hsA.y << 16);
        accA.w = exsA * __uint_as_float(hsA.y & 0xffff0000u);
        accB.x = exsB * __uint_as_float(hsB.x << 16);
        accB.y = exsB * __uint_as_float(hsB.x & 0xffff0000u);
        accB.z = exsB * __uint_as_float(hsB.y << 16);
        accB.w = exsB * __uint_as_float(hsB.y & 0xffff0000u);
    }

    int jA = startA, jB = startB;
    while (jA < endA || jB < endB) {
        bool doA = jA < endA;            // wave-uniform
        bool doB = jB < endB;

        // phase 1: both col loads issued together
        int cvA = nA, cvB = nB;
        if (doA) { int idx = jA + lane; if (lane < U && idx < endA) cvA = col[idx]; }
        if (doB) { int idx = jB + lane; if (lane < U && idx < endB) cvB = col[idx]; }

        // phase 2: index shuffles + ssrcA loads (both nodes) issued
        float s1A = 0.f, s2A = 0.f, s1B = 0.f, s2B = 0.f;
        if (EPEL == 2) {
            int b1A = __shfl(cvA, gb, 64), b2A = __shfl(cvA, gb + U / 2, 64);
            int b1B = __shfl(cvB, gb, 64), b2B = __shfl(cvB, gb + U / 2, 64);
            if (doA) {
                if (jA + gb < endA)         s1A = ssrcA[b1A * H + eh];
                if (jA + gb + U / 2 < endA) s2A = ssrcA[b2A * H + eh];
            }
            if (doB) {
                if (jB + gb < endB)         s1B = ssrcA[b1B * H + eh];
                if (jB + gb + U / 2 < endB) s2B = ssrcA[b2B * H + eh];
            }
        } else {
            int b1A = __shfl(cvA, gb, 64);
            int b1B = __shfl(cvB, gb, 64);
            if (doA && elane && jA + gb < endA) s1A = ssrcA[b1A * H + eh];
            if (doB && elane && jB + gb < endB) s1B = ssrcA[b1B * H + eh];
        }

        // phase 3: all Hbf row gathers issued (unconditional within node guard)
        uint2 hvA[NL], hvB[NL];
        if (doA) {
            #pragma unroll
            for (int t = 0; t < NL; ++t) {
                int se = __shfl(cvA, t * G + pp, 64);
                hvA[t] = Hbf[(size_t)se * CP + cp];
            }
        }
        if (doB) {
            #pragma unroll
            for (int t = 0; t < NL; ++t) {
                int se = __shfl(cvB, t * G + pp, 64);
                hvB[t] = Hbf[(size_t)se * CP + cp];
            }
        }

        // phase 4: exps (consume ssrcA; Hbf gathers still in flight)
        float e1A = 0.f, e2A = 0.f, e1B = 0.f, e2B = 0.f;
        if (EPEL == 2) {
            if (doA) {
                float a1 = sdA + s1A; a1 = (a1 >= 0.f) ? a1 : 0.2f * a1;
                float a2 = sdA + s2A; a2 = (a2 >= 0.f) ? a2 : 0.2f * a2;
                if (jA + gb < endA)         e1A = __expf(a1);
                if (jA + gb + U / 2 < endA) e2A = __expf(a2);
                dsumA += e1A + e2A;
            }
            if (doB) {
                float a1 = sdB + s1B; a1 = (a1 >= 0.f) ? a1 : 0.2f * a1;
                float a2 = sdB + s2B; a2 = (a2 >= 0.f) ? a2 : 0.2f * a2;
                if (jB + gb < endB)         e1B = __expf(a1);
                if (jB + gb + U / 2 < endB) e2B = __expf(a2);
                dsumB += e1B + e2B;
            }
        } else {
            if (doA) {
                float a1 = sdA + s1A; a1 = (a1 >= 0.f) ? a1 : 0.2f * a1;
                if (elane && jA + gb < endA) { e1A = __expf(a1); dsumA += e1A; }
            }
            if (doB) {
                float a1 = sdB + s1B; a1 = (a1 >= 0.f) ? a1 : 0.2f * a1;
                if (elane && jB + gb < endB) { e1B = __expf(a1); dsumB += e1B; }
            }
        }

        // phase 5: consume gathers (dead slots have zero weight)
        if (doA) {
            #pragma unroll
            for (int t = 0; t < NL; ++t) {
                int eidx = t * G + pp;
                float ex;
                if (EPEL == 2)
                    ex = __shfl((t * G + G - 1 < U / 2) ? e1A : e2A, (eidx & (U / 2 - 1)) * H + hh, 64);
                else
                    ex = __shfl(e1A, eidx * H + hh, 64);
                float f0 = __uint_as_float(hvA[t].x << 16);
                float f1 = __uint_as_float(hvA[t].x & 0xffff0000u);
                float f2 = __uint_as_float(hvA[t].y << 16);
                float f3 = __uint_as_float(hvA[t].y & 0xffff0000u);
                accA.x = fmaf(ex, f0, accA.x);
                accA.y = fmaf(ex, f1, accA.y);
                accA.z = fmaf(ex, f2, accA.z);
                accA.w = fmaf(ex, f3, accA.w);
            }
            jA += U;
        }
        if (doB) {
            #pragma unroll
            for (int t = 0; t < NL; ++t) {
                int eidx = t * G + pp;
                float ex;
                if (EPEL == 2)
                    ex = __shfl((t * G + G - 1 < U / 2) ? e1B : e2B, (eidx & (U / 2 - 1)) * H + hh, 64);
                else
                    ex = __shfl(e1B, eidx * H + hh, 64);
                float f0 = __uint_as_float(hvB[t].x << 16);
                float f1 = __uint_as_float(hvB[t].x & 0xffff0000u);
                float f2 = __uint_as_float(hvB[t].y << 16);
                float f3 = __uint_as_float(hvB[t].y & 0xffff0000u);
                accB.x = fmaf(ex, f0, accB.x);
                accB.y = fmaf(ex, f1, accB.y);
                accB.z = fmaf(ex, f2, accB.z);
                accB.w = fmaf(ex, f3, accB.w);
            }
            jB += U;
        }
    }

    // ---- reductions + epilogue, node A ----
    #pragma unroll
    for (int off = H; off < 64; off <<= 1) dsumA += __shfl_xor(dsumA, off, 64);
    float denA = __shfl(dsumA, hh, 64);
    #pragma unroll
    for (int off = CP; off < 64; off <<= 1) {
        accA.x += __shfl_xor(accA.x, off, 64);
        accA.y += __shfl_xor(accA.y, off, 64);
        accA.z += __shfl_xor(accA.z, off, 64);
        accA.w += __shfl_xor(accA.w, off, 64);
    }
    if (lane < CP) {
        float inv = 1.f / denA;
        float4 bv = ((const float4*)bias)[cp];
        float4 v;
        v.x = accA.x * inv + bv.x;
        v.y = accA.y * inv + bv.y;
        v.z = accA.z * inv + bv.z;
        v.w = accA.w * inv + bv.w;
        if (ELU_OUT) {
            v.x = (v.x > 0.f) ? v.x : expm1f(v.x);
            v.y = (v.y > 0.f) ? v.y : expm1f(v.y);
            v.z = (v.z > 0.f) ? v.z : expm1f(v.z);
            v.w = (v.w > 0.f) ? v.w : expm1f(v.w);
        }
        ((float4*)output)[(size_t)nA * CP + cp] = v;
    }

    // ---- reductions + epilogue, node B ----
    if (hasB) {
        #pragma unroll
        for (int off = H; off < 64; off <<= 1) dsumB += __shfl_xor(dsumB, off, 64);
        float denB = __shfl(dsumB, hh, 64);
        #pragma unroll
        for (int off = CP; off < 64; off <<= 1) {
            accB.x += __shfl_xor(accB.x, off, 64);
            accB.y += __shfl_xor(accB.y, off, 64);
            accB.z += __shfl_xor(accB.z, off, 64);
            accB.w += __shfl_xor(accB.w, off, 64);
        }
        if (lane < CP) {
            float inv = 1.f / denB;
            float4 bv = ((const float4*)bias)[cp];
            float4 v;
            v.x = accB.x * inv + bv.x;
            v.y = accB.y * inv + bv.y;
            v.z = accB.z * inv + bv.z;
            v.w = accB.w * inv + bv.w;
            if (ELU_OUT) {
                v.x = (v.x > 0.f) ? v.x : expm1f(v.x);
                v.y = (v.y > 0.f) ? v.y : expm1f(v.y);
                v.z = (v.z > 0.f) ? v.z : expm1f(v.z);
                v.w = (v.w > 0.f) ? v.w : expm1f(v.w);
            }
            ((float4*)output)[(size_t)nB * CP + cp] = v;
        }
    }
}

// ---------------- launch ----------------

extern "C" void kernel_launch(void* const* d_in, const int* in_sizes, int n_in,
                              void* d_out, int out_size, void* d_ws, size_t ws_size,
                              hipStream_t stream) {
    const float* x    = (const float*)d_in[0];
    const int*   ei   = (const int*)d_in[1];
    const float* W1   = (const float*)d_in[2];
    const float* att1 = (const float*)d_in[3];
    const float* b1   = (const float*)d_in[4];
    const float* W2   = (const float*)d_in[5];
    const float* att2 = (const float*)d_in[6];
    const float* b2   = (const float*)d_in[7];
    const float* W3   = (const float*)d_in[8];
    const float* att3 = (const float*)d_in[9];
    const float* b3   = (const float*)d_in[10];
    float* out = (float*)d_out;

    char* p = (char*)d_ws;
    auto alloc = [&](size_t bytes) -> void* {
        void* r = (void*)p;
        p += (bytes + 255) & ~(size_t)255;
        return r;
    };
    int*   rowptr   = (int*)alloc((NN + 1) * sizeof(int));
    int*   deg      = (int*)alloc(NN * sizeof(int));
    int*   CntG     = (int*)alloc((size_t)CH * NN * sizeof(int));
    int*   partials = (int*)alloc(NB_SCAN * sizeof(int));
    int*   col      = (int*)alloc(EE * sizeof(int));
    float* sdst     = (float*)alloc((size_t)NN * 8 * sizeof(float));
    float* ssrcA    = (float*)alloc((size_t)NN * 8 * sizeof(float));
    uint2* Hbf      = (uint2*)alloc((size_t)NN * 16 * sizeof(uint2));
    float* Fb       = (float*)alloc((size_t)NN * 64 * sizeof(float));

    // --- CSR build (dst-grouped, original non-self edges only; no global atomics) ---
    histL_k<<<CH * NR2, 256, 0, stream>>>(ei, CntG);
    combineL_k<<<(NN + 255) / 256, 256, 0, stream>>>(CntG, deg);
    sum_blocks<<<NB_SCAN, 256, 0, stream>>>(deg, partials);
    scan_partials<<<1, 128, 0, stream>>>(partials);
    scan_final<<<NB_SCAN, 256, 0, stream>>>(deg, partials, rowptr);
    scatterL_k<<<CH * NR2, 256, 0, stream>>>(ei, CntG, rowptr, col);

    // --- Layer 1: x[N,128] -> h[N,64]; H=8, C=8; ELU out -> Fb ---
    gemm_tile<128, 64, 8, 64><<<(NN + 63) / 64, 256, 0, stream>>>(x, W1, att1, Hbf, ssrcA, sdst);
    agg_k<64, 8, 16, true><<<(NN + 7) / 8, 256, 0, stream>>>(rowptr, col, sdst, ssrcA, Hbf, b1, Fb);

    // --- Layer 2: Fb[N,64] -> h[N,64]; H=8, C=8; ELU out -> Fb ---
    gemm_tile<64, 64, 8, 64><<<(NN + 63) / 64, 256, 0, stream>>>(Fb, W2, att2, Hbf, ssrcA, sdst);
    agg_k<64, 8, 16, true><<<(NN + 7) / 8, 256, 0, stream>>>(rowptr, col, sdst, ssrcA, Hbf, b2, Fb);

    // --- Layer 3: Fb[N,64] -> h[N,32]; H=1, C=32; no ELU, f32 out -> d_out ---
    gemm_tile<64, 32, 1, 128><<<(NN + 127) / 128, 256, 0, stream>>>(Fb, W3, att3, Hbf, ssrcA, sdst);
    agg_k<32, 1, 32, false><<<(NN + 7) / 8, 256, 0, stream>>>(rowptr, col, sdst, ssrcA, Hbf, b3, out);
}

// Round 3
// 422.615 us; speedup vs baseline: 1.0733x; 1.0733x over previous
//
#include <hip/hip_runtime.h>
#include <hip/hip_bf16.h>

#define NN 100000
#define EE 1600000

constexpr int SCAN_BLK = 1024;                       // elements per scan block (256 thr * 4)
constexpr int NB_SCAN  = (NN + SCAN_BLK - 1) / SCAN_BLK;  // 98

// LDS counting-sort CSR build: 8 dst-ranges x 32 edge-chunks
constexpr int NR2 = 8;              // dst ranges (12500 nodes -> 50 KB LDS histogram)
constexpr int RSZ = NN / NR2;       // 12500
constexpr int CH  = 32;             // edge chunks
constexpr int CSZ = EE / CH;        // 50000 edges per chunk

// ---------------- CSR build (no global atomics) ----------------

__global__ __launch_bounds__(256) void histL_k(const int* __restrict__ ei,
                                               int* __restrict__ CntG) {
    __shared__ int cnt[RSZ];
    int r = blockIdx.x % NR2, c = blockIdx.x / NR2;
    int lo = r * RSZ;
    for (int t = threadIdx.x; t < RSZ; t += 256) cnt[t] = 0;
    __syncthreads();
    const int* __restrict__ dstp = ei + EE;
    int base = c * CSZ;
    int tid = threadIdx.x;
    for (int ii = 0; ii < CSZ; ii += 1024) {
        int d[4], s[4];
        #pragma unroll
        for (int k = 0; k < 4; ++k) {
            int off = ii + tid + k * 256;
            bool v = off < CSZ;
            d[k] = v ? dstp[base + off] : -1;
            s[k] = v ? ei[base + off]   : -1;
        }
        #pragma unroll
        for (int k = 0; k < 4; ++k) {
            int dl = d[k] - lo;
            if (dl >= 0 && dl < RSZ && s[k] != d[k]) atomicAdd(&cnt[dl], 1);
        }
    }
    __syncthreads();
    for (int t = threadIdx.x; t < RSZ; t += 256)
        CntG[(size_t)c * NN + lo + t] = cnt[t];
}

__global__ void combineL_k(int* __restrict__ CntG, int* __restrict__ deg) {
    int d = blockIdx.x * 256 + threadIdx.x;
    if (d < NN) {
        int run = 0;
        #pragma unroll 8
        for (int c = 0; c < CH; ++c) {
            int v = CntG[(size_t)c * NN + d];
            CntG[(size_t)c * NN + d] = run;
            run += v;
        }
        deg[d] = run;
    }
}

__global__ void sum_blocks(const int* __restrict__ deg, int* __restrict__ partials) {
    __shared__ int sh[256];
    int t = threadIdx.x;
    int base = blockIdx.x * SCAN_BLK + t * 4;
    int s = 0;
    #pragma unroll
    for (int k = 0; k < 4; ++k) { int i = base + k; if (i < NN) s += deg[i]; }
    sh[t] = s; __syncthreads();
    for (int off = 128; off > 0; off >>= 1) {
        if (t < off) sh[t] += sh[t + off];
        __syncthreads();
    }
    if (t == 0) partials[blockIdx.x] = sh[0];
}

__global__ void scan_partials(int* __restrict__ partials) {
    __shared__ int sh[128];
    int t = threadIdx.x;
    int v = (t < NB_SCAN) ? partials[t] : 0;
    sh[t] = v;
    __syncthreads();
    for (int off = 1; off < 128; off <<= 1) {
        int tmp = (t >= off) ? sh[t - off] : 0;
        __syncthreads();
        sh[t] += tmp;
        __syncthreads();
    }
    if (t < NB_SCAN) partials[t] = sh[t] - v;   // exclusive prefix
}

__global__ void scan_final(const int* __restrict__ deg, const int* __restrict__ partials,
                           int* __restrict__ rowptr) {
    __shared__ int sh[256];
    int t = threadIdx.x;
    int base = blockIdx.x * SCAN_BLK + t * 4;
    int v[4]; int s = 0;
    #pragma unroll
    for (int k = 0; k < 4; ++k) { int i = base + k; v[k] = (i < NN) ? deg[i] : 0; s += v[k]; }
    sh[t] = s; __syncthreads();
    for (int off = 1; off < 256; off <<= 1) {
        int tmp = (t >= off) ? sh[t - off] : 0;
        __syncthreads();
        sh[t] += tmp;
        __syncthreads();
    }
    int pref = partials[blockIdx.x] + sh[t] - s;
    #pragma unroll
    for (int k = 0; k < 4; ++k) {
        int i = base + k;
        if (i < NN) {
            rowptr[i] = pref; pref += v[k];
            if (i == NN - 1) rowptr[NN] = pref;
        }
    }
}

__global__ __launch_bounds__(256) void scatterL_k(const int* __restrict__ ei,
                                                  const int* __restrict__ CntG,
                                                  const int* __restrict__ rowptr,
                                                  int* __restrict__ col) {
    __shared__ int cur[RSZ];
    int r = blockIdx.x % NR2, c = blockIdx.x / NR2;
    int lo = r * RSZ;
    for (int t = threadIdx.x; t < RSZ; t += 256)
        cur[t] = rowptr[lo + t] + CntG[(size_t)c * NN + lo + t];
    __syncthreads();
    const int* __restrict__ dstp = ei + EE;
    int base = c * CSZ;
    int tid = threadIdx.x;
    for (int ii = 0; ii < CSZ; ii += 1024) {
        int d[4], s[4];
        #pragma unroll
        for (int k = 0; k < 4; ++k) {
            int off = ii + tid + k * 256;
            bool v = off < CSZ;
            d[k] = v ? dstp[base + off] : -1;
            s[k] = v ? ei[base + off]   : -1;
        }
        #pragma unroll
        for (int k = 0; k < 4; ++k) {
            int dl = d[k] - lo;
            if (dl >= 0 && dl < RSZ && s[k] != d[k]) {
                int p = atomicAdd(&cur[dl], 1);
                col[p] = s[k];
            }
        }
    }
}

// ---------------- GEMM (h = x @ W) + per-node attention arrays ----------------

template<int K, int M, int H, int NPB>
__global__ __launch_bounds__(256) void gemm_tile(const float* __restrict__ xin,
                          const float* __restrict__ W,
                          const float* __restrict__ att,
                          uint2* __restrict__ Hbf,
                          float* __restrict__ ssrcA,
                          float* __restrict__ sdst) {
    constexpr int C   = M / H;
    constexpr int MG  = M / 4;               // col-groups (4 cols per thread)
    constexpr int NG  = NPB / 4;
    static_assert(MG * NG == 256, "tile mismatch");
    constexpr int K4  = K / 4;
    constexpr int KC4 = (K4 > 16) ? 16 : K4;
    constexpr int NCH = K4 / KC4;

    __shared__ float4 Wq[K * MG];
    __shared__ float4 Xq[NPB * KC4];

    int tid = threadIdx.x;
    const float4* W4 = (const float4*)W;
    for (int i = tid; i < K * MG; i += 256) Wq[i] = W4[i];

    int node0 = blockIdx.x * NPB;
    const float4* x4 = (const float4*)xin;

    int mg = tid % MG, ng = tid / MG;
    int nb = ng * 4;
    float acc[4][4];
    #pragma unroll
    for (int i = 0; i < 4; ++i)
        #pragma unroll
        for (int j = 0; j < 4; ++j) acc[i][j] = 0.f;

    for (int ch = 0; ch < NCH; ++ch) {
        __syncthreads();
        for (int i = tid; i < NPB * KC4; i += 256) {
            int n = i / KC4, k4l = i % KC4;
            int node = node0 + n;
            float4 v = make_float4(0.f, 0.f, 0.f, 0.f);
            if (node < NN) v = x4[(size_t)node * K4 + ch * KC4 + k4l];
            Xq[i] = v;
        }
        __syncthreads();
        #pragma unroll 4
        for (int k4 = 0; k4 < KC4; ++k4) {
            float4 xv[4], wv[4];
            #pragma unroll
            for (int i = 0; i < 4; ++i) xv[i] = Xq[(nb + i) * KC4 + k4];
            int kbase = (ch * KC4 + k4) * 4;
            #pragma unroll
            for (int kk = 0; kk < 4; ++kk) wv[kk] = Wq[(kbase + kk) * MG + mg];
            #pragma unroll
            for (int i = 0; i < 4; ++i) {
                const float* xf = (const float*)&xv[i];
                #pragma unroll
                for (int kk = 0; kk < 4; ++kk) {
                    const float* wf = (const float*)&wv[kk];
                    float xs = xf[kk];
                    acc[i][0] = fmaf(xs, wf[0], acc[i][0]);
                    acc[i][1] = fmaf(xs, wf[1], acc[i][1]);
                    acc[i][2] = fmaf(xs, wf[2], acc[i][2]);
                    acc[i][3] = fmaf(xs, wf[3], acc[i][3]);
                }
            }
        }
    }

    constexpr int TPH = C / 4;               // threads covering one head's cols
    int head = mg / TPH;
    int c0   = (mg % TPH) * 4;
    float ad[4], as_[4];
    #pragma unroll
    for (int j = 0; j < 4; ++j) {
        ad[j]  = att[head * 2 * C + c0 + j];
        as_[j] = att[head * 2 * C + C + c0 + j];
    }
    #pragma unroll
    for (int i = 0; i < 4; ++i) {
        int node = node0 + nb + i;
        if (node < NN) {
            unsigned short us[4];
            #pragma unroll
            for (int j = 0; j < 4; ++j) {
                __hip_bfloat16 b = __float2bfloat16(acc[i][j]);
                us[j] = *(unsigned short*)&b;
            }
            uint2 pk;
            pk.x = (unsigned)us[0] | ((unsigned)us[1] << 16);
            pk.y = (unsigned)us[2] | ((unsigned)us[3] << 16);
            Hbf[(size_t)node * MG + mg] = pk;
        }
        float pd = acc[i][0]*ad[0]  + acc[i][1]*ad[1]  + acc[i][2]*ad[2]  + acc[i][3]*ad[3];
        float ps = acc[i][0]*as_[0] + acc[i][1]*as_[1] + acc[i][2]*as_[2] + acc[i][3]*as_[3];
        #pragma unroll
        for (int off = 1; off < TPH; off <<= 1) {
            pd += __shfl_xor(pd, off, 64);
            ps += __shfl_xor(ps, off, 64);
        }
        if ((mg % TPH) == 0 && node < NN) {
            sdst[node * H + head]  = pd;
            ssrcA[node * H + head] = ps;
        }
    }
}

// ---------------- Aggregation: one wave per node (baseline skeleton) ----------
// Same structure as the 425-us baseline: 100K waves, unconditional clamped
// gathers, predicated-exp masking (no load-serializing guards). Deltas vs
// baseline, both latency-chain only:
//   1. All NL Hbf gathers issued BEFORE the exp computation, so the ssrcA
//      wait + exp hide under the gather latency.
//   2. Next iteration's col chunk prefetched while gathers are in flight
//      (single wave-uniform guard placed AFTER gather issue).
//   3. Virtual self-loop in the prologue (coalesced own-row read, loop runs
//      over real edges only: mean iterations/node 1.54 -> 1.44).

template<int CT, int H, int U, bool ELU_OUT>
__global__ __launch_bounds__(256) void agg_k(const int* __restrict__ rowptr, const int* __restrict__ col,
                      const float* __restrict__ sdst, const float* __restrict__ ssrcA,
                      const uint2* __restrict__ Hbf,
                      const float* __restrict__ bias, float* __restrict__ output) {
    constexpr int C    = CT / H;         // channels per head
    constexpr int CP   = CT / 4;         // lanes covering one row (uint2 = 4 ch)
    constexpr int G    = 64 / CP;        // edge slots per gather instruction
    constexpr int NL   = U / G;          // row gathers in flight per lane
    constexpr int EPEL = (U * H >= 64) ? (U * H) / 64 : 1;   // edges per exp lane
    static_assert(EPEL == 1 || EPEL == 2, "mapping");

    int lane = threadIdx.x & 63;
    int node = blockIdx.x * (blockDim.x >> 6) + (threadIdx.x >> 6);
    if (node >= NN) return;

    int cp = lane % CP;                  // channel quad {4cp..4cp+3}
    int pp = lane / CP;                  // gather slot parity (0..G-1)
    int hh = (4 * cp) / C;               // head of these channels (uniform in quad)
    int eh = lane % H;                   // exp-lane head
    int gb = lane / H;                   // exp-lane base edge slot
    bool elane = (lane < U * H);         // exp-lane mask (EPEL==1 case)

    float sd = elane ? sdst[node * H + eh] : 0.f;

    int start = rowptr[node], end = rowptr[node + 1];

    // ---- virtual self-loop: score + own-row contribution (coalesced) ----
    float dsum = 0.f;
    float e_self = 0.f;
    if (lane < H) {                      // lane == eh, gb == 0
        float ss = ssrcA[node * H + lane];
        float a = sd + ss; a = (a >= 0.f) ? a : 0.2f * a;
        e_self = __expf(a);
        dsum = e_self;
    }
    uint2 hs = Hbf[(size_t)node * CP + cp];
    float exs = __shfl(e_self, hh, 64);
    float4 acc = make_float4(0.f, 0.f, 0.f, 0.f);
    if (pp == 0) {                       // count self row exactly once
        acc.x = exs * __uint_as_float(hs.x << 16);
        acc.y = exs * __uint_as_float(hs.x & 0xffff0000u);
        acc.z = exs * __uint_as_float(hs.y << 16);
        acc.w = exs * __uint_as_float(hs.y & 0xffff0000u);
    }

    // first col chunk
    int cv = node;
    if (start < end) {
        int idx = start + lane;
        if (lane < U && idx < end) cv = col[idx];
    }

    for (int j = start; j < end; j += U) {
        // shuffles of current col chunk (feed both ssrcA and Hbf addressing)
        float s1 = 0.f, s2 = 0.f;
        int b1 = 0, b2 = 0;
        if (EPEL == 2) {
            b1 = __shfl(cv, gb, 64);
            b2 = __shfl(cv, gb + U / 2, 64);
            s1 = ssrcA[b1 * H + eh];     // issued; dead slots clamped to node (cached)
            s2 = ssrcA[b2 * H + eh];
        } else {
            b1 = __shfl(cv, gb, 64);
            if (elane) s1 = ssrcA[b1 * H + eh];
        }

        // issue ALL row gathers back-to-back (depend only on cv)
        uint2 hv[NL];
        #pragma unroll
        for (int t = 0; t < NL; ++t) {
            int se = __shfl(cv, t * G + pp, 64);
            hv[t] = Hbf[(size_t)se * CP + cp];
        }

        // prefetch next col chunk while gathers are in flight
        int jn = j + U;
        int cvN = node;
        if (jn < end) {                  // wave-uniform; after gather issue
            int idx = jn + lane;
            if (lane < U && idx < end) cvN = col[idx];
        }

        // exps (consume ssrcA; Hbf gathers still in flight)
        float e1 = 0.f, e2 = 0.f;
        if (EPEL == 2) {
            float a1 = sd + s1; a1 = (a1 >= 0.f) ? a1 : 0.2f * a1;
            float a2 = sd + s2; a2 = (a2 >= 0.f) ? a2 : 0.2f * a2;
            if (j + gb < end)         e1 = __expf(a1);
            if (j + gb + U / 2 < end) e2 = __expf(a2);
            dsum += e1 + e2;
        } else {
            float a1 = sd + s1; a1 = (a1 >= 0.f) ? a1 : 0.2f * a1;
            if (elane && j + gb < end) { e1 = __expf(a1); dsum += e1; }
        }

        // consume gathers (dead slots have zero weight)
        #pragma unroll
        for (int t = 0; t < NL; ++t) {
            int eidx = t * G + pp;
            float ex;
            if (EPEL == 2)
                ex = __shfl((t * G + G - 1 < U / 2) ? e1 : e2, (eidx & (U / 2 - 1)) * H + hh, 64);
            else
                ex = __shfl(e1, eidx * H + hh, 64);
            float f0 = __uint_as_float(hv[t].x << 16);
            float f1 = __uint_as_float(hv[t].x & 0xffff0000u);
            float f2 = __uint_as_float(hv[t].y << 16);
            float f3 = __uint_as_float(hv[t].y & 0xffff0000u);
            acc.x = fmaf(ex, f0, acc.x);
            acc.y = fmaf(ex, f1, acc.y);
            acc.z = fmaf(ex, f2, acc.z);
            acc.w = fmaf(ex, f3, acc.w);
        }
        cv = cvN;
    }

    // reduce dsum over edge-slot lanes (masked lanes contribute 0)
    #pragma unroll
    for (int off = H; off < 64; off <<= 1) dsum += __shfl_xor(dsum, off, 64);
    float den = __shfl(dsum, hh, 64);    // lane 'hh' holds head hh's full sum
    // reduce acc over gather-slot parities
    #pragma unroll
    for (int off = CP; off < 64; off <<= 1) {
        acc.x += __shfl_xor(acc.x, off, 64);
        acc.y += __shfl_xor(acc.y, off, 64);
        acc.z += __shfl_xor(acc.z, off, 64);
        acc.w += __shfl_xor(acc.w, off, 64);
    }
    if (lane < CP) {
        float inv = 1.f / den;
        float4 bv = ((const float4*)bias)[cp];
        float4 v;
        v.x = acc.x * inv + bv.x;
        v.y = acc.y * inv + bv.y;
        v.z = acc.z * inv + bv.z;
        v.w = acc.w * inv + bv.w;
        if (ELU_OUT) {
            v.x = (v.x > 0.f) ? v.x : expm1f(v.x);   // ELU(alpha=1)
            v.y = (v.y > 0.f) ? v.y : expm1f(v.y);
            v.z = (v.z > 0.f) ? v.z : expm1f(v.z);
            v.w = (v.w > 0.f) ? v.w : expm1f(v.w);
        }
        ((float4*)output)[(size_t)node * CP + cp] = v;
    }
}

// ---------------- launch ----------------

extern "C" void kernel_launch(void* const* d_in, const int* in_sizes, int n_in,
                              void* d_out, int out_size, void* d_ws, size_t ws_size,
                              hipStream_t stream) {
    const float* x    = (const float*)d_in[0];
    const int*   ei   = (const int*)d_in[1];
    const float* W1   = (const float*)d_in[2];
    const float* att1 = (const float*)d_in[3];
    const float* b1   = (const float*)d_in[4];
    const float* W2   = (const float*)d_in[5];
    const float* att2 = (const float*)d_in[6];
    const float* b2   = (const float*)d_in[7];
    const float* W3   = (const float*)d_in[8];
    const float* att3 = (const float*)d_in[9];
    const float* b3   = (const float*)d_in[10];
    float* out = (float*)d_out;

    char* p = (char*)d_ws;
    auto alloc = [&](size_t bytes) -> void* {
        void* r = (void*)p;
        p += (bytes + 255) & ~(size_t)255;
        return r;
    };
    int*   rowptr   = (int*)alloc((NN + 1) * sizeof(int));
    int*   deg      = (int*)alloc(NN * sizeof(int));
    int*   CntG     = (int*)alloc((size_t)CH * NN * sizeof(int));
    int*   partials = (int*)alloc(NB_SCAN * sizeof(int));
    int*   col      = (int*)alloc(EE * sizeof(int));
    float* sdst     = (float*)alloc((size_t)NN * 8 * sizeof(float));
    float* ssrcA    = (float*)alloc((size_t)NN * 8 * sizeof(float));
    uint2* Hbf      = (uint2*)alloc((size_t)NN * 16 * sizeof(uint2));
    float* Fb       = (float*)alloc((size_t)NN * 64 * sizeof(float));

    // --- CSR build (dst-grouped, original non-self edges only; no global atomics) ---
    histL_k<<<CH * NR2, 256, 0, stream>>>(ei, CntG);
    combineL_k<<<(NN + 255) / 256, 256, 0, stream>>>(CntG, deg);
    sum_blocks<<<NB_SCAN, 256, 0, stream>>>(deg, partials);
    scan_partials<<<1, 128, 0, stream>>>(partials);
    scan_final<<<NB_SCAN, 256, 0, stream>>>(deg, partials, rowptr);
    scatterL_k<<<CH * NR2, 256, 0, stream>>>(ei, CntG, rowptr, col);

    // --- Layer 1: x[N,128] -> h[N,64]; H=8, C=8; ELU out -> Fb ---
    gemm_tile<128, 64, 8, 64><<<(NN + 63) / 64, 256, 0, stream>>>(x, W1, att1, Hbf, ssrcA, sdst);
    agg_k<64, 8, 16, true><<<(NN + 3) / 4, 256, 0, stream>>>(rowptr, col, sdst, ssrcA, Hbf, b1, Fb);

    // --- Layer 2: Fb[N,64] -> h[N,64]; H=8, C=8; ELU out -> Fb ---
    gemm_tile<64, 64, 8, 64><<<(NN + 63) / 64, 256, 0, stream>>>(Fb, W2, att2, Hbf, ssrcA, sdst);
    agg_k<64, 8, 16, true><<<(NN + 3) / 4, 256, 0, stream>>>(rowptr, col, sdst, ssrcA, Hbf, b2, Fb);

    // --- Layer 3: Fb[N,64] -> h[N,32]; H=1, C=32; no ELU, f32 out -> d_out ---
    gemm_tile<64, 32, 1, 128><<<(NN + 127) / 128, 256, 0, stream>>>(Fb, W3, att3, Hbf, ssrcA, sdst);
    agg_k<32, 1, 32, false><<<(NN + 3) / 4, 256, 0, stream>>>(rowptr, col, sdst, ssrcA, Hbf, b3, out);
}